// Round 1
// baseline (60.027 us; speedup 1.0000x reference)
//
#include <hip/hip_runtime.h>
#include <math.h>

#define M       32
#define IDIM    64
#define DIN     68
#define HDIM    128
#define ROWS    4

// workspace float offsets
#define OFF_A     0        // A[i][d]   = sum_h Wq[i,h]*Wk[d,h]      (64x68)
#define OFF_U0    4352     // u0[d]     = sum_h Wk[d,h]*bq[h]        (68)
#define OFF_G     4420     // g[i]      = sum_h Wq[i,h]*bk[h]        (64)
#define OFF_C0    4484     // c0        = bq.bk                      (1)
#define OFF_WVO   4608     // Wvo[d][j] = sum_h Wv[d,h]*Wo[h,j]      (68x64)
#define OFF_OUTB  8960     // outb[j]   = sum_h bv[h]*Wo[h,j] + bo[j] (64)
#define WS_FLOATS 9024

__global__ __launch_bounds__(256)
void ga_precompute(const float* __restrict__ Wq, const float* __restrict__ bq,
                   const float* __restrict__ Wk, const float* __restrict__ bk,
                   const float* __restrict__ Wv, const float* __restrict__ bv,
                   const float* __restrict__ Wo, const float* __restrict__ bo,
                   float* __restrict__ ws) {
  int t = blockIdx.x * 256 + threadIdx.x;
  if (t < 4352) {                       // A
    int i = t / DIN, d = t % DIN;
    float acc = 0.f;
    #pragma unroll 8
    for (int h = 0; h < HDIM; ++h) acc = fmaf(Wq[i*HDIM+h], Wk[d*HDIM+h], acc);
    ws[OFF_A + t] = acc;
  } else if (t < 4420) {                // u0
    int d = t - 4352;
    float acc = 0.f;
    for (int h = 0; h < HDIM; ++h) acc = fmaf(Wk[d*HDIM+h], bq[h], acc);
    ws[OFF_U0 + d] = acc;
  } else if (t < 4484) {                // g
    int i = t - 4420;
    float acc = 0.f;
    for (int h = 0; h < HDIM; ++h) acc = fmaf(Wq[i*HDIM+h], bk[h], acc);
    ws[OFF_G + i] = acc;
  } else if (t == 4484) {               // c0
    float acc = 0.f;
    for (int h = 0; h < HDIM; ++h) acc = fmaf(bq[h], bk[h], acc);
    ws[OFF_C0] = acc;
  } else if (t >= OFF_WVO && t < OFF_WVO + 4352) {   // Wvo
    int e = t - OFF_WVO;
    int d = e >> 6, j = e & 63;
    float acc = 0.f;
    #pragma unroll 8
    for (int h = 0; h < HDIM; ++h) acc = fmaf(Wv[d*HDIM+h], Wo[h*IDIM+j], acc);
    ws[OFF_WVO + e] = acc;
  } else if (t >= OFF_OUTB && t < OFF_OUTB + IDIM) { // outb
    int j = t - OFF_OUTB;
    float acc = bo[j];
    for (int h = 0; h < HDIM; ++h) acc = fmaf(bv[h], Wo[h*IDIM+j], acc);
    ws[OFF_OUTB + j] = acc;
  }
}

__global__ __launch_bounds__(256, 4)
void ga_main(const float* __restrict__ ego,
             const float* __restrict__ nz,
             const float* __restrict__ rp,
             const int*   __restrict__ mask,
             const float* __restrict__ ws,
             float* __restrict__ out) {
  __shared__ float zs_lds[ROWS * M * IDIM];   // 4 x 2048 f32
  __shared__ float rp_lds[ROWS * M * 4];      // 4 x 128
  __shared__ float qk_lds[ROWS * 72];
  __shared__ float w_lds [ROWS * M];
  __shared__ float fb_lds[ROWS * 72];

  const int tid  = threadIdx.x;
  const int wave = tid >> 6;
  const int lane = tid & 63;
  const int row  = __builtin_amdgcn_readfirstlane(blockIdx.x * ROWS + wave);

  const int zb = wave * (M * IDIM);
  const int rb = wave * (M * 4);
  const int qb = wave * 72;
  const int fbb = wave * 72;

  // ---- stage neighbor features into registers (loads in flight over phase 1) ----
  const float4* zsrc4 = (const float4*)(nz + (size_t)row * (M * IDIM));
  float4 zreg[8];
  #pragma unroll
  for (int it = 0; it < 8; ++it) zreg[it] = zsrc4[it * 64 + lane];
  const float4* rpsrc4 = (const float4*)(rp + (size_t)row * (M * 4));
  float4 rpreg = rpsrc4[lane & 31];
  const int mreg = mask[row * M + (lane & 31)];

  // ---- phase 1: u = ego @ A + u0  (lane = output dim d, 0..63) ----
  const float* egoR = ego + (size_t)row * IDIM;   // uniform -> scalar loads
  float uacc = 0.f;
  #pragma unroll 8
  for (int i = 0; i < IDIM; ++i)
    uacc = fmaf(egoR[i], ws[OFF_A + i * DIN + lane], uacc);
  uacc += ws[OFF_U0 + lane];
  qk_lds[qb + lane] = uacc;

  // tail dims 64..67 (cooperative 16-lane dots)
  {
    int t4 = lane >> 4, i0 = (lane & 15) * 4;
    float pt = 0.f;
    #pragma unroll
    for (int k = 0; k < 4; ++k)
      pt = fmaf(egoR[i0 + k], ws[OFF_A + (i0 + k) * DIN + IDIM + t4], pt);
    pt += __shfl_xor(pt, 1);
    pt += __shfl_xor(pt, 2);
    pt += __shfl_xor(pt, 4);
    pt += __shfl_xor(pt, 8);
    if ((lane & 15) == 0) qk_lds[qb + IDIM + t4] = pt + ws[OFF_U0 + IDIM + t4];
  }

  // c = ego . g + c0  (zero with default biases, kept for exactness)
  float pc = egoR[lane] * ws[OFF_G + lane];
  pc += __shfl_xor(pc, 1);
  pc += __shfl_xor(pc, 2);
  pc += __shfl_xor(pc, 4);
  pc += __shfl_xor(pc, 8);
  pc += __shfl_xor(pc, 16);
  pc += __shfl_xor(pc, 32);
  const float cterm = pc + ws[OFF_C0];

  // ---- park staged features in LDS ----
  #pragma unroll
  for (int it = 0; it < 8; ++it)
    *(float4*)&zs_lds[zb + it * 256 + lane * 4] = zreg[it];
  if (lane < 32) *(float4*)&rp_lds[rb + (lane & 31) * 4] = rpreg;

  __syncthreads();

  // ---- phase 2: scores + softmax. lane = (m, half) ----
  const int m = lane & 31;
  const int h = lane >> 5;
  float sacc = 0.f;
  #pragma unroll 8
  for (int j = 0; j < 32; ++j) {
    int d = h * 32 + ((j + m) & 31);          // rotation: bank-conflict-free
    sacc = fmaf(zs_lds[zb + m * IDIM + d], qk_lds[qb + d], sacc);
  }
  if (h) {
    #pragma unroll
    for (int t2 = 0; t2 < 4; ++t2)
      sacc = fmaf(rp_lds[rb + m * 4 + t2], qk_lds[qb + IDIM + t2], sacc);
  } else {
    sacc += cterm;
  }
  sacc += __shfl_xor(sacc, 32);               // combine halves: full dot

  float s = (mreg != 0) ? sacc * 0.088388347648318447f : -1e9f;  // 1/sqrt(128)
  float mx = s;
  mx = fmaxf(mx, __shfl_xor(mx, 1));
  mx = fmaxf(mx, __shfl_xor(mx, 2));
  mx = fmaxf(mx, __shfl_xor(mx, 4));
  mx = fmaxf(mx, __shfl_xor(mx, 8));
  mx = fmaxf(mx, __shfl_xor(mx, 16));
  float e = __expf(s - mx);
  float se = e;
  se += __shfl_xor(se, 1);
  se += __shfl_xor(se, 2);
  se += __shfl_xor(se, 4);
  se += __shfl_xor(se, 8);
  se += __shfl_xor(se, 16);
  float w = e / se;
  if (h == 0) w_lds[wave * M + m] = w;

  __syncthreads();

  // ---- phase 3: fbar[d] = sum_m w_m * feats[m][d]  (lane = d) ----
  float fbv = 0.f;
  #pragma unroll 8
  for (int mm = 0; mm < M; ++mm)
    fbv = fmaf(w_lds[wave * M + mm], zs_lds[zb + mm * IDIM + lane], fbv);
  fb_lds[fbb + lane] = fbv;
  {
    int t4 = lane >> 4, ii = lane & 15;
    float p3 = w_lds[wave * M + ii]      * rp_lds[rb + ii * 4 + t4]
             + w_lds[wave * M + ii + 16] * rp_lds[rb + (ii + 16) * 4 + t4];
    p3 += __shfl_xor(p3, 1);
    p3 += __shfl_xor(p3, 2);
    p3 += __shfl_xor(p3, 4);
    p3 += __shfl_xor(p3, 8);
    if (ii == 0) fb_lds[fbb + IDIM + t4] = p3;
  }

  __syncthreads();

  // ---- phase 4: out = fbar @ Wvo + outb  (lane = output dim j) ----
  float oacc = ws[OFF_OUTB + lane];
  #pragma unroll 4
  for (int d = 0; d < DIN; ++d)
    oacc = fmaf(fb_lds[fbb + d], ws[OFF_WVO + d * IDIM + lane], oacc);
  out[(size_t)row * IDIM + lane] = oacc;
}

extern "C" void kernel_launch(void* const* d_in, const int* in_sizes, int n_in,
                              void* d_out, int out_size, void* d_ws, size_t ws_size,
                              hipStream_t stream) {
  const float* ego = (const float*)d_in[0];
  const float* nz  = (const float*)d_in[1];
  const float* rp  = (const float*)d_in[2];
  const int*   mk  = (const int*)d_in[3];
  const float* Wq  = (const float*)d_in[4];
  const float* bq  = (const float*)d_in[5];
  const float* Wk  = (const float*)d_in[6];
  const float* bk  = (const float*)d_in[7];
  const float* Wv  = (const float*)d_in[8];
  const float* bv  = (const float*)d_in[9];
  const float* Wo  = (const float*)d_in[10];
  const float* bo  = (const float*)d_in[11];
  float* ws = (float*)d_ws;   // needs WS_FLOATS*4 = 36096 bytes
  float* o  = (float*)d_out;

  const int nrows = in_sizes[0] / IDIM;   // 16384

  ga_precompute<<<(WS_FLOATS + 255) / 256, 256, 0, stream>>>(
      Wq, bq, Wk, bk, Wv, bv, Wo, bo, ws);
  ga_main<<<nrows / ROWS, 256, 0, stream>>>(ego, nz, rp, mk, ws, o);
}

// Round 2
// 48.994 us; speedup vs baseline: 1.2252x; 1.2252x over previous
//
#include <hip/hip_runtime.h>
#include <math.h>

#define M       32
#define IDIM    64
#define DIN     68
#define HDIM    128

// workspace float offsets
#define OFF_A     0        // A[i][d]   = sum_h Wq[i,h]*Wk[d,h]      (64x68)
#define OFF_U0    4352     // u0[d]     = sum_h Wk[d,h]*bq[h]        (68)
#define OFF_G     4420     // g[i]      = sum_h Wq[i,h]*bk[h]        (64)
#define OFF_C0    4484     // c0        = bq.bk                      (1)
#define OFF_WVO   4608     // Wvo[d][j] = sum_h Wv[d,h]*Wo[h,j]      (68x64)
#define OFF_OUTB  8960     // outb[j]   = sum_h bv[h]*Wo[h,j] + bo[j] (64)
#define WS_FLOATS 9024

__global__ __launch_bounds__(256)
void ga_precompute(const float* __restrict__ Wq, const float* __restrict__ bq,
                   const float* __restrict__ Wk, const float* __restrict__ bk,
                   const float* __restrict__ Wv, const float* __restrict__ bv,
                   const float* __restrict__ Wo, const float* __restrict__ bo,
                   float* __restrict__ ws) {
  int t = blockIdx.x * 256 + threadIdx.x;
  if (t < 4352) {                       // A
    int i = t / DIN, d = t % DIN;
    float acc = 0.f;
    #pragma unroll 8
    for (int h = 0; h < HDIM; ++h) acc = fmaf(Wq[i*HDIM+h], Wk[d*HDIM+h], acc);
    ws[OFF_A + t] = acc;
  } else if (t < 4420) {                // u0
    int d = t - 4352;
    float acc = 0.f;
    for (int h = 0; h < HDIM; ++h) acc = fmaf(Wk[d*HDIM+h], bq[h], acc);
    ws[OFF_U0 + d] = acc;
  } else if (t < 4484) {                // g
    int i = t - 4420;
    float acc = 0.f;
    for (int h = 0; h < HDIM; ++h) acc = fmaf(Wq[i*HDIM+h], bk[h], acc);
    ws[OFF_G + i] = acc;
  } else if (t == 4484) {               // c0
    float acc = 0.f;
    for (int h = 0; h < HDIM; ++h) acc = fmaf(bq[h], bk[h], acc);
    ws[OFF_C0] = acc;
  } else if (t >= OFF_WVO && t < OFF_WVO + 4352) {   // Wvo
    int e = t - OFF_WVO;
    int d = e >> 6, j = e & 63;
    float acc = 0.f;
    #pragma unroll 8
    for (int h = 0; h < HDIM; ++h) acc = fmaf(Wv[d*HDIM+h], Wo[h*IDIM+j], acc);
    ws[OFF_WVO + e] = acc;
  } else if (t >= OFF_OUTB && t < OFF_OUTB + IDIM) { // outb
    int j = t - OFF_OUTB;
    float acc = bo[j];
    for (int h = 0; h < HDIM; ++h) acc = fmaf(bv[h], Wo[h*IDIM+j], acc);
    ws[OFF_OUTB + j] = acc;
  }
}

// One wave per batch row. Fully wave-local: no __syncthreads, ~2.8KB LDS/block.
// Register layout (from coalesced float4 staging): zreg[it] holds
// feats[m][d0..d0+3] with m = it*4 + (lane>>4), d0 = (lane&15)*4.
__global__ __launch_bounds__(256, 5)
void ga_main(const float* __restrict__ ego,
             const float* __restrict__ nz,
             const float* __restrict__ rp,
             const int*   __restrict__ mask,
             const float* __restrict__ ws,
             float* __restrict__ out) {
  __shared__ float u_lds [4 * 72];
  __shared__ float sc_lds[4 * 32];
  __shared__ float fb_lds[4 * 72];

  const int tid  = threadIdx.x;
  const int wave = tid >> 6;
  const int lane = tid & 63;
  const int row  = __builtin_amdgcn_readfirstlane(blockIdx.x * 4 + wave);

  const int ub  = wave * 72;
  const int sb  = wave * 32;
  const int fbb = wave * 72;

  // ---- staging loads: issued first, in flight across phase 1 ----
  const float4* zsrc4 = (const float4*)(nz + (size_t)row * (M * IDIM));
  float4 zreg[8];
  #pragma unroll
  for (int it = 0; it < 8; ++it) zreg[it] = zsrc4[it * 64 + lane];
  const float4 rpreg = ((const float4*)(rp + (size_t)row * (M * 4)))[lane & 31];
  const int    mreg  = mask[row * M + (lane & 31)];

  // ---- phase 1: u[d] = ego @ A + u0, lane = d ----
  const float* egoR = ego + (size_t)row * IDIM;   // wave-uniform -> scalar loads
  {
    float ua0 = 0.f, ua1 = 0.f, ua2 = 0.f, ua3 = 0.f;
    #pragma unroll 4
    for (int i = 0; i < IDIM; i += 4) {
      ua0 = fmaf(egoR[i],     ws[OFF_A + (i)     * DIN + lane], ua0);
      ua1 = fmaf(egoR[i + 1], ws[OFF_A + (i + 1) * DIN + lane], ua1);
      ua2 = fmaf(egoR[i + 2], ws[OFF_A + (i + 2) * DIN + lane], ua2);
      ua3 = fmaf(egoR[i + 3], ws[OFF_A + (i + 3) * DIN + lane], ua3);
    }
    u_lds[ub + lane] = ((ua0 + ua1) + (ua2 + ua3)) + ws[OFF_U0 + lane];
  }
  // tail dims u[64..67]: 16-lane cooperative dots
  {
    int t4 = lane >> 4, i0 = (lane & 15) * 4;
    float pt = 0.f;
    #pragma unroll
    for (int k = 0; k < 4; ++k)
      pt = fmaf(egoR[i0 + k], ws[OFF_A + (i0 + k) * DIN + IDIM + t4], pt);
    pt += __shfl_xor(pt, 1);
    pt += __shfl_xor(pt, 2);
    pt += __shfl_xor(pt, 4);
    pt += __shfl_xor(pt, 8);
    if ((lane & 15) == 0) u_lds[ub + IDIM + t4] = pt + ws[OFF_U0 + IDIM + t4];
  }
  // cterm = ego.g + c0 (exactness with nonzero biases)
  float cterm;
  {
    float pc = egoR[lane] * ws[OFF_G + lane];
    pc += __shfl_xor(pc, 1);
    pc += __shfl_xor(pc, 2);
    pc += __shfl_xor(pc, 4);
    pc += __shfl_xor(pc, 8);
    pc += __shfl_xor(pc, 16);
    pc += __shfl_xor(pc, 32);
    cterm = pc + ws[OFF_C0];
  }

  asm volatile("" ::: "memory");   // in-wave DS order: writes above before reads below

  // ---- phase 2: scores from registers ----
  const float4 u4 = *(const float4*)&u_lds[ub + (lane & 15) * 4];
  #pragma unroll
  for (int it = 0; it < 8; ++it) {
    float p = zreg[it].x * u4.x;
    p = fmaf(zreg[it].y, u4.y, p);
    p = fmaf(zreg[it].z, u4.z, p);
    p = fmaf(zreg[it].w, u4.w, p);
    p += __shfl_xor(p, 1);
    p += __shfl_xor(p, 2);
    p += __shfl_xor(p, 4);
    p += __shfl_xor(p, 8);
    if ((lane & 15) == 0) sc_lds[sb + it * 4 + (lane >> 4)] = p;
  }

  asm volatile("" ::: "memory");

  const float uh0 = u_lds[ub + 64], uh1 = u_lds[ub + 65];
  const float uh2 = u_lds[ub + 66], uh3 = u_lds[ub + 67];
  float sraw = sc_lds[sb + (lane & 31)] + cterm;
  sraw = fmaf(rpreg.x, uh0, sraw);
  sraw = fmaf(rpreg.y, uh1, sraw);
  sraw = fmaf(rpreg.z, uh2, sraw);
  sraw = fmaf(rpreg.w, uh3, sraw);

  float s = (mreg != 0) ? sraw * 0.088388347648318447f : -1e9f;  // 1/sqrt(128)
  float mx = s;
  mx = fmaxf(mx, __shfl_xor(mx, 1));
  mx = fmaxf(mx, __shfl_xor(mx, 2));
  mx = fmaxf(mx, __shfl_xor(mx, 4));
  mx = fmaxf(mx, __shfl_xor(mx, 8));
  mx = fmaxf(mx, __shfl_xor(mx, 16));
  float e = __expf(s - mx);
  float se = e;
  se += __shfl_xor(se, 1);
  se += __shfl_xor(se, 2);
  se += __shfl_xor(se, 4);
  se += __shfl_xor(se, 8);
  se += __shfl_xor(se, 16);
  const float w = e / se;

  // ---- phase 3: fbar from registers ----
  float p40 = 0.f, p41 = 0.f, p42 = 0.f, p43 = 0.f;
  #pragma unroll
  for (int it = 0; it < 8; ++it) {
    float wit = __shfl(w, it * 4 + (lane >> 4));
    p40 = fmaf(wit, zreg[it].x, p40);
    p41 = fmaf(wit, zreg[it].y, p41);
    p42 = fmaf(wit, zreg[it].z, p42);
    p43 = fmaf(wit, zreg[it].w, p43);
  }
  p40 += __shfl_xor(p40, 16);  p40 += __shfl_xor(p40, 32);
  p41 += __shfl_xor(p41, 16);  p41 += __shfl_xor(p41, 32);
  p42 += __shfl_xor(p42, 16);  p42 += __shfl_xor(p42, 32);
  p43 += __shfl_xor(p43, 16);  p43 += __shfl_xor(p43, 32);
  if (lane < 16) {
    float4 fv; fv.x = p40; fv.y = p41; fv.z = p42; fv.w = p43;
    *(float4*)&fb_lds[fbb + lane * 4] = fv;
  }
  // rp contribution to fbar[64..67]
  {
    float pr0 = w * rpreg.x, pr1 = w * rpreg.y, pr2 = w * rpreg.z, pr3 = w * rpreg.w;
    pr0 += __shfl_xor(pr0, 1); pr1 += __shfl_xor(pr1, 1);
    pr2 += __shfl_xor(pr2, 1); pr3 += __shfl_xor(pr3, 1);
    pr0 += __shfl_xor(pr0, 2); pr1 += __shfl_xor(pr1, 2);
    pr2 += __shfl_xor(pr2, 2); pr3 += __shfl_xor(pr3, 2);
    pr0 += __shfl_xor(pr0, 4); pr1 += __shfl_xor(pr1, 4);
    pr2 += __shfl_xor(pr2, 4); pr3 += __shfl_xor(pr3, 4);
    pr0 += __shfl_xor(pr0, 8); pr1 += __shfl_xor(pr1, 8);
    pr2 += __shfl_xor(pr2, 8); pr3 += __shfl_xor(pr3, 8);
    pr0 += __shfl_xor(pr0, 16); pr1 += __shfl_xor(pr1, 16);
    pr2 += __shfl_xor(pr2, 16); pr3 += __shfl_xor(pr3, 16);
    if (lane == 0) {
      float4 fv; fv.x = pr0; fv.y = pr1; fv.z = pr2; fv.w = pr3;
      *(float4*)&fb_lds[fbb + IDIM] = fv;
    }
  }

  asm volatile("" ::: "memory");

  // ---- phase 4: out[j] = fbar @ Wvo + outb, lane = j ----
  float oa0 = 0.f, oa1 = 0.f, oa2 = 0.f, oa3 = 0.f;
  #pragma unroll 4
  for (int d = 0; d < DIN; d += 4) {
    oa0 = fmaf(fb_lds[fbb + d],     ws[OFF_WVO + (d)     * IDIM + lane], oa0);
    oa1 = fmaf(fb_lds[fbb + d + 1], ws[OFF_WVO + (d + 1) * IDIM + lane], oa1);
    oa2 = fmaf(fb_lds[fbb + d + 2], ws[OFF_WVO + (d + 2) * IDIM + lane], oa2);
    oa3 = fmaf(fb_lds[fbb + d + 3], ws[OFF_WVO + (d + 3) * IDIM + lane], oa3);
  }
  out[(size_t)row * IDIM + lane] = ((oa0 + oa1) + (oa2 + oa3)) + ws[OFF_OUTB + lane];
}

extern "C" void kernel_launch(void* const* d_in, const int* in_sizes, int n_in,
                              void* d_out, int out_size, void* d_ws, size_t ws_size,
                              hipStream_t stream) {
  const float* ego = (const float*)d_in[0];
  const float* nz  = (const float*)d_in[1];
  const float* rp  = (const float*)d_in[2];
  const int*   mk  = (const int*)d_in[3];
  const float* Wq  = (const float*)d_in[4];
  const float* bq  = (const float*)d_in[5];
  const float* Wk  = (const float*)d_in[6];
  const float* bk  = (const float*)d_in[7];
  const float* Wv  = (const float*)d_in[8];
  const float* bv  = (const float*)d_in[9];
  const float* Wo  = (const float*)d_in[10];
  const float* bo  = (const float*)d_in[11];
  float* ws = (float*)d_ws;   // needs WS_FLOATS*4 = 36096 bytes
  float* o  = (float*)d_out;

  const int nrows = in_sizes[0] / IDIM;   // 16384

  ga_precompute<<<(WS_FLOATS + 255) / 256, 256, 0, stream>>>(
      Wq, bq, Wk, bk, Wv, bv, Wo, bo, ws);
  ga_main<<<nrows / 4, 256, 0, stream>>>(ego, nz, rp, mk, ws, o);
}